// Round 22
// baseline (232.336 us; speedup 1.0000x reference)
//
#include <hip/hip_runtime.h>
#include <hip/hip_fp16.h>
#include <cstdint>

typedef _Float16 h16;
typedef _Float16 half8 __attribute__((ext_vector_type(8)));
typedef float floatx4 __attribute__((ext_vector_type(4)));

#define T_SZ 60
#define H_SZ 128
#define NB_FC1 7680   // T*H = 60*128
#define NKT   240     // NB_FC1 / 32

#define LOG2E  1.44269504088896340736f
#define LOG2E2 2.88539008177792681472f

__device__ __forceinline__ float sigm(float x) {
    float e = __builtin_amdgcn_exp2f(x * -LOG2E);
    return __builtin_amdgcn_rcpf(1.0f + e);
}
__device__ __forceinline__ float tanh_f(float x) {
    float e = __builtin_amdgcn_exp2f(x * LOG2E2);   // exp(2x)
    return 1.0f - 2.0f * __builtin_amdgcn_rcpf(e + 1.0f);
}

// ---------------------------------------------------------------------------
// Fused LSTM layer (proven R13/R16 step schedule, 99 us/layer, no spill)
// + POST-LOOP FC head (FUSE_FC, layer 2): 3-slot distance-2 pipeline.
// R22: BOTH fc operands now K-major contiguous —
//   WcT[ktg][64][32] (R21, b-loads = contiguous 1KB/wave) and
//   h2T[block][ktg][16][32], ktg = t*4 + (c>>5) (NEW, a-loads = contiguous
//   1KB/wave; flush stores fully coalesced). flat k = ktg*32+(c&31) = t*128+c
//   matches WcT's tiling -> contraction identical.
// block = 16 batch rows x 60 timesteps, grid 256, 512 threads (8 waves,
// 1 block/CU). Step order: hf ds_reads -> x-part of t+1 -> h-MFMAs ->
// acts -> ring write -> barrier. DO NOT reorder (R15 spilled).
// ---------------------------------------------------------------------------
template<int INDIM, bool IN_F32, bool FUSE_FC>
__global__ __launch_bounds__(512, 1)
void lstm_layer(const void* __restrict__ in_v,
                const float* __restrict__ W_ih,
                const float* __restrict__ W_hh,
                const float* __restrict__ b_ih,
                const float* __restrict__ b_hh,
                h16* __restrict__ h_out,         // !FUSE_FC: [B][T][H]; FUSE_FC: h2T
                const h16* __restrict__ WcT,     // FUSE_FC: [240][64][32]
                const float* __restrict__ bcv,   // FUSE_FC: [60]
                float* __restrict__ out)         // FUSE_FC: [B][60]
{
    constexpr int KT_IN = INDIM / 32;
    __shared__ __align__(16) h16 hist[16][16][H_SZ];   // 64 KB swizzled ring

    const int tid  = threadIdx.x;
    const int w    = tid >> 6;
    const int lane = tid & 63;
    const int lrow = lane & 15;   // A-row / B-col within tile
    const int lgrp = lane >> 4;   // k-group
    const size_t base_row = (size_t)blockIdx.x * 16;

    // -------- register-resident B-fragments of W_ih / W_hh (fp32 -> fp16) ----
    half8 wf_in[4][KT_IN];
    half8 wf_hh[4][4];
    float bias[4];

    #pragma unroll
    for (int q = 0; q < 4; ++q) {
        const int n = (w + 8 * q) * 16 + lrow;      // gate row (0..511)
        bias[q] = b_ih[n] + b_hh[n];
        #pragma unroll
        for (int kt = 0; kt < KT_IN; ++kt) {
            const float* p = W_ih + (size_t)n * INDIM + kt * 32 + lgrp * 8;
            half8 v;
            #pragma unroll
            for (int j = 0; j < 8; ++j) v[j] = (h16)p[j];
            wf_in[q][kt] = v;
        }
        #pragma unroll
        for (int kt = 0; kt < 4; ++kt) {
            const float* p = W_hh + (size_t)n * H_SZ + kt * 32 + lgrp * 8;
            half8 v;
            #pragma unroll
            for (int j = 0; j < 8; ++j) v[j] = (h16)p[j];
            wf_hh[q][kt] = v;
        }
    }

    const float* inF = (const float*)in_v;
    const h16*   inH = (const h16*)in_v;

    // single x slot; loaded ~1 full step before consumption
    floatx4 raw[KT_IN][2];
    half8   xs[KT_IN];

    auto load_x = [&](int t) {
        #pragma unroll
        for (int kt = 0; kt < KT_IN; ++kt) {
            if constexpr (IN_F32) {
                const float* p = inF + ((base_row + lrow) * T_SZ + t) * INDIM + kt * 32 + lgrp * 8;
                raw[kt][0] = *(const floatx4*)(p);
                raw[kt][1] = *(const floatx4*)(p + 4);
            } else {
                xs[kt] = *(const half8*)(inH + ((base_row + lrow) * T_SZ + t) * INDIM + kt * 32 + lgrp * 8);
            }
        }
    };

    auto get_x = [&](half8 (&xf)[KT_IN]) {   // consume-point packed cvt (RTZ)
        #pragma unroll
        for (int kt = 0; kt < KT_IN; ++kt) {
            if constexpr (IN_F32) {
                const auto p0 = __builtin_amdgcn_cvt_pkrtz(raw[kt][0][0], raw[kt][0][1]);
                const auto p1 = __builtin_amdgcn_cvt_pkrtz(raw[kt][0][2], raw[kt][0][3]);
                const auto p2 = __builtin_amdgcn_cvt_pkrtz(raw[kt][1][0], raw[kt][1][1]);
                const auto p3 = __builtin_amdgcn_cvt_pkrtz(raw[kt][1][2], raw[kt][1][3]);
                half8 v;
                v[0] = (h16)p0[0]; v[1] = (h16)p0[1]; v[2] = (h16)p1[0]; v[3] = (h16)p1[1];
                v[4] = (h16)p2[0]; v[5] = (h16)p2[1]; v[6] = (h16)p3[0]; v[7] = (h16)p3[1];
                xf[kt] = v;
            } else {
                xf[kt] = xs[kt];
            }
        }
    };

    floatx4 c4 = {0.f, 0.f, 0.f, 0.f};
    const int colW = 16 * w + lrow;   // this lane's h-column

    // ---- flush: stores h(t-7..t) --------------------------------------------
    // !FUSE_FC: row-major [row][t][H] (consumed by next layer's load_x).
    // FUSE_FC: K-major h2T[ktg][16][32], fully coalesced 8KB store groups.
    auto flush = [&](int t) {
        if constexpr (FUSE_FC) {
            h16* blk = h_out + (size_t)blockIdx.x * 16 * NB_FC1;
            #pragma unroll
            for (int s = 0; s < 4; ++s) {
                const int u   = tid + 512 * s;      // 16B-chunk index, 0..2047
                const int tl  = u >> 8;             // window slot 0..7
                const int g   = (u >> 6) & 3;       // col group
                const int row = (u >> 2) & 15;
                const int c2  = u & 3;
                const int col = g * 32 + c2 * 8;
                const half8 v = *(const half8*)&hist[(t - 7 + tl) & 15][row][col ^ ((row & 7) << 3)];
                const int ktg = (t - 7 + tl) * 4 + g;
                *(half8*)(blk + ((size_t)ktg * 16 + row) * 32 + c2 * 8) = v;
            }
        } else {
            half8 vals[4];
            int   time[4], row[4], cg[4];
            #pragma unroll
            for (int s = 0; s < 4; ++s) {
                const int u = tid + 512 * s;        // 0..2047
                time[s] = t - 7 + (u >> 8);
                row[s]  = (u >> 4) & 15;
                cg[s]   = u & 15;
                vals[s] = *(const half8*)&hist[time[s] & 15][row[s]][(cg[s] * 8) ^ ((row[s] & 7) << 3)];
            }
            #pragma unroll
            for (int s = 0; s < 4; ++s)
                *(half8*)(h_out + ((base_row + row[s]) * T_SZ + time[s]) * H_SZ + cg[s] * 8) = vals[s];
        }
    };

    // -------- prologue: accA = bias + x-part(0); prefetch x(1) ---------------
    floatx4 accA[4], accB[4];
    load_x(0);
    {
        half8 xf[KT_IN];
        get_x(xf);
        #pragma unroll
        for (int q = 0; q < 4; ++q) accA[q] = floatx4{bias[q], bias[q], bias[q], bias[q]};
        #pragma unroll
        for (int kt = 0; kt < KT_IN; ++kt)
            #pragma unroll
            for (int q = 0; q < 4; ++q)
                accA[q] = __builtin_amdgcn_mfma_f32_16x16x32_f16(xf[kt], wf_in[q][kt], accA[q], 0, 0, 0);
        load_x(1);
    }

    auto step = [&](int t, floatx4 (&accC)[4], floatx4 (&accN)[4]) {
        // ---- issue hf ds_reads first --------------------------------------
        half8 hf[4];
        const bool have_h = (t > 0);
        if (have_h) {
            const h16* hb = &hist[(t - 1) & 15][0][0];
            #pragma unroll
            for (int kt = 0; kt < 4; ++kt) {
                const int col0 = kt * 32 + lgrp * 8;
                hf[kt] = *(const half8*)(hb + lrow * H_SZ + (col0 ^ ((lrow & 7) << 3)));
            }
        }

        // ---- x-part of step t+1 overlaps the ds_read latency --------------
        if (t + 1 < T_SZ) {
            half8 xf[KT_IN];
            get_x(xf);
            #pragma unroll
            for (int q = 0; q < 4; ++q) accN[q] = floatx4{bias[q], bias[q], bias[q], bias[q]};
            #pragma unroll
            for (int kt = 0; kt < KT_IN; ++kt)
                #pragma unroll
                for (int q = 0; q < 4; ++q)
                    accN[q] = __builtin_amdgcn_mfma_f32_16x16x32_f16(xf[kt], wf_in[q][kt], accN[q], 0, 0, 0);
            if (t + 2 < T_SZ) load_x(t + 2);
        }

        // ---- h-MFMAs on the critical path (accC already holds bias+x(t)) ---
        if (have_h) {
            #pragma unroll
            for (int kt = 0; kt < 4; ++kt)
                #pragma unroll
                for (int q = 0; q < 4; ++q)
                    accC[q] = __builtin_amdgcn_mfma_f32_16x16x32_f16(hf[kt], wf_hh[q][kt], accC[q], 0, 0, 0);
        }

        // ---- activations + cell update + ring write ------------------------
        h16 hcast[4];
        #pragma unroll
        for (int r = 0; r < 4; ++r) {
            const float gi = sigm(accC[0][r]);
            const float gf = sigm(accC[1][r]);
            const float gg = tanh_f(accC[2][r]);
            const float go = sigm(accC[3][r]);
            const float cc = gf * c4[r] + gi * gg;
            c4[r] = cc;
            hcast[r] = (h16)(go * tanh_f(cc));
        }
        h16* hb2 = &hist[t & 15][0][0];
        #pragma unroll
        for (int r = 0; r < 4; ++r) {
            const int rowW = lgrp * 4 + r;
            hb2[rowW * H_SZ + (colW ^ ((rowW & 7) << 3))] = hcast[r];
        }

        // raw barrier: wait only on LDS (x loads stay in flight)
        asm volatile("s_waitcnt lgkmcnt(0)" ::: "memory");
        __builtin_amdgcn_s_barrier();
        asm volatile("" ::: "memory");

        if (((t & 7) == 7) || (t == T_SZ - 1)) flush(t);
    };

    #pragma unroll 1
    for (int tt = 0; tt < T_SZ; tt += 2) {
        step(tt,     accA, accB);
        step(tt + 1, accB, accA);
    }

    // -------- FUSE_FC: post-loop FC head, 3-slot distance-2 pipeline ---------
    if constexpr (FUSE_FC) {
        __syncthreads();   // drain h2T stores; block-visible, L2/L3-hot reread

        floatx4 afc[4];
        #pragma unroll
        for (int q = 0; q < 4; ++q) afc[q] = floatx4{0.f, 0.f, 0.f, 0.f};

        const h16* blk = h_out + (size_t)blockIdx.x * 16 * NB_FC1;

        auto ld = [&](int i, half8& a, half8 (&b)[4]) {   // ktg = w*30 + i
            const int ktg = w * 30 + i;
            // h2T[ktg][lrow][lgrp*8]: wave reads one contiguous 1KB run
            a = *(const half8*)(blk + ((size_t)ktg * 16 + lrow) * 32 + lgrp * 8);
            #pragma unroll
            for (int q = 0; q < 4; ++q) {
                const int n = q * 16 + lrow;
                b[q] = 0;
                if (n < 60)   // WcT[ktg][n][lgrp*8]: contiguous 1KB run
                    b[q] = *(const half8*)(WcT + ((size_t)ktg * 64 + n) * 32 + lgrp * 8);
            }
        };
        auto mm4 = [&](const half8& a, const half8 (&b)[4]) {
            #pragma unroll
            for (int q = 0; q < 4; ++q)
                afc[q] = __builtin_amdgcn_mfma_f32_16x16x32_f16(a, b[q], afc[q], 0, 0, 0);
        };

        half8 a0, a1, a2, b0[4], b1[4], b2[4];
        ld(0, a0, b0);
        ld(1, a1, b1);
        #pragma unroll 1
        for (int i = 0; i < 30; i += 3) {            // 30 % 3 == 0
            ld(i + 2, a2, b2);                       // distance-2 prefetch
            mm4(a0, b0);
            if (i + 3 < 30) ld(i + 3, a0, b0);
            mm4(a1, b1);
            if (i + 4 < 30) ld(i + 4, a1, b1);
            mm4(a2, b2);
        }

        // 8-wave reduction through the (dead) ring LDS: 8*4*16*16 f32 = 16KB
        float* red = (float*)&hist[0][0][0];
        #pragma unroll
        for (int q = 0; q < 4; ++q)
            #pragma unroll
            for (int r = 0; r < 4; ++r)
                red[(((w * 4 + q) * 16) + (lgrp * 4 + r)) * 16 + lrow] = afc[q][r];
        __syncthreads();

        #pragma unroll
        for (int s = 0; s < 2; ++s) {
            const int idx = tid + 512 * s;       // 16 rows x 64 cols
            const int row = idx >> 6, col = idx & 63;
            if (col < 60) {
                const int q = col >> 4, cin = col & 15;
                float v = 0.f;
                #pragma unroll
                for (int ww = 0; ww < 8; ++ww)
                    v += red[(((ww * 4 + q) * 16) + row) * 16 + cin];
                out[(base_row + row) * 60 + col] = v + bcv[col];
            }
        }
    }
}

// ---------------------------------------------------------------------------
// Merged head-precompute kernel, grid 180:
//  blocks 0..119 : WcT[ktg][64][32] (K-major folded head weight)
//  blocks 120..179: bc[m] = W_fc2[m]@b_fc1 + b_fc2[m] (m = bid-120)
// ---------------------------------------------------------------------------
__global__ __launch_bounds__(256, 2)
void head_kernel(const float* __restrict__ W_fc1,   // [512][7680]
                 const float* __restrict__ W_fc2,   // [60][512]
                 const float* __restrict__ b_fc1,   // [512]
                 const float* __restrict__ b_fc2,   // [60]
                 h16* __restrict__ WcT,             // [240][64][32]
                 float* __restrict__ bc)            // [60]
{
    const int tid  = threadIdx.x;
    if (blockIdx.x >= 120) {
        const int m = blockIdx.x - 120;
        const int t = tid;
        float p = W_fc2[m * 512 + t] * b_fc1[t] + W_fc2[m * 512 + 256 + t] * b_fc1[256 + t];
        #pragma unroll
        for (int off = 1; off < 64; off <<= 1) p += __shfl_xor(p, off);
        __shared__ float sred[4];
        if ((t & 63) == 0) sred[t >> 6] = p;
        __syncthreads();
        if (t == 0) bc[m] = sred[0] + sred[1] + sred[2] + sred[3] + b_fc2[m];
        return;
    }

    const int wv   = tid >> 6;
    const int lane = tid & 63;
    const int lrow = lane & 15;
    const int lgrp = lane >> 4;
    const int j0   = blockIdx.x * 64 + wv * 16;   // this wave's 16 output cols

    floatx4 acc[4];
    #pragma unroll
    for (int mt = 0; mt < 4; ++mt) acc[mt] = floatx4{0.f, 0.f, 0.f, 0.f};

    for (int kt = 0; kt < 16; ++kt) {
        const int k0 = kt * 32 + lgrp * 8;
        half8 bf;
        #pragma unroll
        for (int i = 0; i < 8; ++i)
            bf[i] = (h16)W_fc1[(size_t)(k0 + i) * NB_FC1 + j0 + lrow];
        #pragma unroll
        for (int mt = 0; mt < 4; ++mt) {
            const int m = mt * 16 + lrow;
            half8 af = {};
            if (m < 60) {
                const float* p = W_fc2 + (size_t)m * 512 + k0;
                const floatx4 f0 = *(const floatx4*)(p);
                const floatx4 f1 = *(const floatx4*)(p + 4);
                const auto p0 = __builtin_amdgcn_cvt_pkrtz(f0[0], f0[1]);
                const auto p1 = __builtin_amdgcn_cvt_pkrtz(f0[2], f0[3]);
                const auto p2 = __builtin_amdgcn_cvt_pkrtz(f1[0], f1[1]);
                const auto p3 = __builtin_amdgcn_cvt_pkrtz(f1[2], f1[3]);
                af[0] = (h16)p0[0]; af[1] = (h16)p0[1]; af[2] = (h16)p1[0]; af[3] = (h16)p1[1];
                af[4] = (h16)p2[0]; af[5] = (h16)p2[1]; af[6] = (h16)p3[0]; af[7] = (h16)p3[1];
            }
            acc[mt] = __builtin_amdgcn_mfma_f32_16x16x32_f16(af, bf, acc[mt], 0, 0, 0);
        }
    }

    // D[row m = mt*16+lgrp*4+r][col j = j0+lrow] -> WcT[(j>>5)][m][j&31]
    #pragma unroll
    for (int mt = 0; mt < 4; ++mt)
        #pragma unroll
        for (int r = 0; r < 4; ++r) {
            const int m = mt * 16 + lgrp * 4 + r;
            const int j = j0 + lrow;
            if (m < 60)
                WcT[((size_t)(j >> 5) * 64 + m) * 32 + (j & 31)] = (h16)acc[mt][r];
        }
}

extern "C" void kernel_launch(void* const* d_in, const int* in_sizes, int n_in,
                              void* d_out, int out_size, void* d_ws, size_t ws_size,
                              hipStream_t stream)
{
    const float* X      = (const float*)d_in[0];
    const float* W_ih1  = (const float*)d_in[1];
    const float* W_hh1  = (const float*)d_in[2];
    const float* b_ih1  = (const float*)d_in[3];
    const float* b_hh1  = (const float*)d_in[4];
    const float* W_ih2  = (const float*)d_in[5];
    const float* W_hh2  = (const float*)d_in[6];
    const float* b_ih2  = (const float*)d_in[7];
    const float* b_hh2  = (const float*)d_in[8];
    const float* W_fc1  = (const float*)d_in[9];
    const float* b_fc1  = (const float*)d_in[10];
    const float* W_fc2  = (const float*)d_in[11];
    const float* b_fc2  = (const float*)d_in[12];

    // workspace: h1 (63MB) | h2T (63MB) | WcT (0.94MB) | bc
    h16* h1  = (h16*)d_ws;
    h16* h2  = h1 + (size_t)4096 * NB_FC1;
    h16* WcT = h2 + (size_t)4096 * NB_FC1;
    float* bc = (float*)(WcT + (size_t)NKT * 64 * 32);

    head_kernel<<<180, 256, 0, stream>>>(W_fc1, W_fc2, b_fc1, b_fc2, WcT, bc);
    lstm_layer<64,  true,  false><<<256, 512, 0, stream>>>(
        (const void*)X,  W_ih1, W_hh1, b_ih1, b_hh1, h1, nullptr, nullptr, nullptr);
    lstm_layer<128, false, true ><<<256, 512, 0, stream>>>(
        (const void*)h1, W_ih2, W_hh2, b_ih2, b_hh2, h2, WcT, bc, (float*)d_out);
}

// Round 23
// 212.479 us; speedup vs baseline: 1.0935x; 1.0935x over previous
//
#include <hip/hip_runtime.h>
#include <hip/hip_fp16.h>
#include <cstdint>

typedef _Float16 h16;
typedef _Float16 half8 __attribute__((ext_vector_type(8)));
typedef float floatx4 __attribute__((ext_vector_type(4)));

#define T_SZ 60
#define H_SZ 128
#define NB_FC1 7680   // T*H = 60*128
#define NKT   240     // NB_FC1 / 32

#define LOG2E  1.44269504088896340736f
#define LOG2E2 2.88539008177792681472f

__device__ __forceinline__ float sigm(float x) {
    float e = __builtin_amdgcn_exp2f(x * -LOG2E);
    return __builtin_amdgcn_rcpf(1.0f + e);
}
__device__ __forceinline__ float tanh_f(float x) {
    float e = __builtin_amdgcn_exp2f(x * LOG2E2);   // exp(2x)
    return 1.0f - 2.0f * __builtin_amdgcn_rcpf(e + 1.0f);
}

// ---------------------------------------------------------------------------
// Fused LSTM layer (proven R13/R16 step schedule, 99 us/layer, no spill)
// + POST-LOOP FC head (FUSE_FC, layer 2): 3-slot distance-2 pipeline, with
// Wc in K-MAJOR-TRANSPOSED layout WcT[kt][64][32] so each b-load reads ONE
// contiguous 1KB run. h2 stays ROW-MAJOR [row][t][H] (R22's K-major h2T
// variant regressed 122->140 us — do not revisit).
// block = 16 batch rows x 60 timesteps, grid 256, 512 threads (8 waves,
// 1 block/CU). Step order: hf ds_reads -> x-part of t+1 -> h-MFMAs ->
// acts -> ring write -> barrier. DO NOT reorder (R15 spilled).
// ---------------------------------------------------------------------------
template<int INDIM, bool IN_F32, bool FUSE_FC>
__global__ __launch_bounds__(512, 1)
void lstm_layer(const void* __restrict__ in_v,
                const float* __restrict__ W_ih,
                const float* __restrict__ W_hh,
                const float* __restrict__ b_ih,
                const float* __restrict__ b_hh,
                h16* __restrict__ h_out,
                const h16* __restrict__ WcT,     // FUSE_FC: [240][64][32]
                const float* __restrict__ bcv,   // FUSE_FC: [60]
                float* __restrict__ out)         // FUSE_FC: [B][60]
{
    constexpr int KT_IN = INDIM / 32;
    __shared__ __align__(16) h16 hist[16][16][H_SZ];   // 64 KB swizzled ring

    const int tid  = threadIdx.x;
    const int w    = tid >> 6;
    const int lane = tid & 63;
    const int lrow = lane & 15;   // A-row / B-col within tile
    const int lgrp = lane >> 4;   // k-group
    const size_t base_row = (size_t)blockIdx.x * 16;

    // -------- register-resident B-fragments of W_ih / W_hh (fp32 -> fp16) ----
    half8 wf_in[4][KT_IN];
    half8 wf_hh[4][4];
    float bias[4];

    #pragma unroll
    for (int q = 0; q < 4; ++q) {
        const int n = (w + 8 * q) * 16 + lrow;      // gate row (0..511)
        bias[q] = b_ih[n] + b_hh[n];
        #pragma unroll
        for (int kt = 0; kt < KT_IN; ++kt) {
            const float* p = W_ih + (size_t)n * INDIM + kt * 32 + lgrp * 8;
            half8 v;
            #pragma unroll
            for (int j = 0; j < 8; ++j) v[j] = (h16)p[j];
            wf_in[q][kt] = v;
        }
        #pragma unroll
        for (int kt = 0; kt < 4; ++kt) {
            const float* p = W_hh + (size_t)n * H_SZ + kt * 32 + lgrp * 8;
            half8 v;
            #pragma unroll
            for (int j = 0; j < 8; ++j) v[j] = (h16)p[j];
            wf_hh[q][kt] = v;
        }
    }

    const float* inF = (const float*)in_v;
    const h16*   inH = (const h16*)in_v;

    // single x slot; loaded ~1 full step before consumption
    floatx4 raw[KT_IN][2];
    half8   xs[KT_IN];

    auto load_x = [&](int t) {
        #pragma unroll
        for (int kt = 0; kt < KT_IN; ++kt) {
            if constexpr (IN_F32) {
                const float* p = inF + ((base_row + lrow) * T_SZ + t) * INDIM + kt * 32 + lgrp * 8;
                raw[kt][0] = *(const floatx4*)(p);
                raw[kt][1] = *(const floatx4*)(p + 4);
            } else {
                xs[kt] = *(const half8*)(inH + ((base_row + lrow) * T_SZ + t) * INDIM + kt * 32 + lgrp * 8);
            }
        }
    };

    auto get_x = [&](half8 (&xf)[KT_IN]) {   // consume-point packed cvt (RTZ)
        #pragma unroll
        for (int kt = 0; kt < KT_IN; ++kt) {
            if constexpr (IN_F32) {
                const auto p0 = __builtin_amdgcn_cvt_pkrtz(raw[kt][0][0], raw[kt][0][1]);
                const auto p1 = __builtin_amdgcn_cvt_pkrtz(raw[kt][0][2], raw[kt][0][3]);
                const auto p2 = __builtin_amdgcn_cvt_pkrtz(raw[kt][1][0], raw[kt][1][1]);
                const auto p3 = __builtin_amdgcn_cvt_pkrtz(raw[kt][1][2], raw[kt][1][3]);
                half8 v;
                v[0] = (h16)p0[0]; v[1] = (h16)p0[1]; v[2] = (h16)p1[0]; v[3] = (h16)p1[1];
                v[4] = (h16)p2[0]; v[5] = (h16)p2[1]; v[6] = (h16)p3[0]; v[7] = (h16)p3[1];
                xf[kt] = v;
            } else {
                xf[kt] = xs[kt];
            }
        }
    };

    floatx4 c4 = {0.f, 0.f, 0.f, 0.f};
    const int colW = 16 * w + lrow;   // this lane's h-column

    auto flush = [&](int t) {   // stores h(t-7..t); ring half disjoint from next writes
        half8 vals[4];
        int   time[4], row[4], cg[4];
        #pragma unroll
        for (int s = 0; s < 4; ++s) {
            const int u = tid + 512 * s;        // 0..2047
            time[s] = t - 7 + (u >> 8);
            row[s]  = (u >> 4) & 15;
            cg[s]   = u & 15;
            vals[s] = *(const half8*)&hist[time[s] & 15][row[s]][(cg[s] * 8) ^ ((row[s] & 7) << 3)];
        }
        #pragma unroll
        for (int s = 0; s < 4; ++s)
            *(half8*)(h_out + ((base_row + row[s]) * T_SZ + time[s]) * H_SZ + cg[s] * 8) = vals[s];
    };

    // -------- prologue: accA = bias + x-part(0); prefetch x(1) ---------------
    floatx4 accA[4], accB[4];
    load_x(0);
    {
        half8 xf[KT_IN];
        get_x(xf);
        #pragma unroll
        for (int q = 0; q < 4; ++q) accA[q] = floatx4{bias[q], bias[q], bias[q], bias[q]};
        #pragma unroll
        for (int kt = 0; kt < KT_IN; ++kt)
            #pragma unroll
            for (int q = 0; q < 4; ++q)
                accA[q] = __builtin_amdgcn_mfma_f32_16x16x32_f16(xf[kt], wf_in[q][kt], accA[q], 0, 0, 0);
        load_x(1);
    }

    auto step = [&](int t, floatx4 (&accC)[4], floatx4 (&accN)[4]) {
        // ---- issue hf ds_reads first --------------------------------------
        half8 hf[4];
        const bool have_h = (t > 0);
        if (have_h) {
            const h16* hb = &hist[(t - 1) & 15][0][0];
            #pragma unroll
            for (int kt = 0; kt < 4; ++kt) {
                const int col0 = kt * 32 + lgrp * 8;
                hf[kt] = *(const half8*)(hb + lrow * H_SZ + (col0 ^ ((lrow & 7) << 3)));
            }
        }

        // ---- x-part of step t+1 overlaps the ds_read latency --------------
        if (t + 1 < T_SZ) {
            half8 xf[KT_IN];
            get_x(xf);
            #pragma unroll
            for (int q = 0; q < 4; ++q) accN[q] = floatx4{bias[q], bias[q], bias[q], bias[q]};
            #pragma unroll
            for (int kt = 0; kt < KT_IN; ++kt)
                #pragma unroll
                for (int q = 0; q < 4; ++q)
                    accN[q] = __builtin_amdgcn_mfma_f32_16x16x32_f16(xf[kt], wf_in[q][kt], accN[q], 0, 0, 0);
            if (t + 2 < T_SZ) load_x(t + 2);
        }

        // ---- h-MFMAs on the critical path (accC already holds bias+x(t)) ---
        if (have_h) {
            #pragma unroll
            for (int kt = 0; kt < 4; ++kt)
                #pragma unroll
                for (int q = 0; q < 4; ++q)
                    accC[q] = __builtin_amdgcn_mfma_f32_16x16x32_f16(hf[kt], wf_hh[q][kt], accC[q], 0, 0, 0);
        }

        // ---- activations + cell update + ring write ------------------------
        h16 hcast[4];
        #pragma unroll
        for (int r = 0; r < 4; ++r) {
            const float gi = sigm(accC[0][r]);
            const float gf = sigm(accC[1][r]);
            const float gg = tanh_f(accC[2][r]);
            const float go = sigm(accC[3][r]);
            const float cc = gf * c4[r] + gi * gg;
            c4[r] = cc;
            hcast[r] = (h16)(go * tanh_f(cc));
        }
        h16* hb2 = &hist[t & 15][0][0];
        #pragma unroll
        for (int r = 0; r < 4; ++r) {
            const int rowW = lgrp * 4 + r;
            hb2[rowW * H_SZ + (colW ^ ((rowW & 7) << 3))] = hcast[r];
        }

        // raw barrier: wait only on LDS (x loads stay in flight)
        asm volatile("s_waitcnt lgkmcnt(0)" ::: "memory");
        __builtin_amdgcn_s_barrier();
        asm volatile("" ::: "memory");

        if (((t & 7) == 7) || (t == T_SZ - 1)) flush(t);
    };

    #pragma unroll 1
    for (int tt = 0; tt < T_SZ; tt += 2) {
        step(tt,     accA, accB);
        step(tt + 1, accB, accA);
    }

    // -------- FUSE_FC: post-loop FC head, 3-slot distance-2 pipeline ---------
    if constexpr (FUSE_FC) {
        __syncthreads();   // drain h2 stores; block-visible, L2/L3-hot reread

        floatx4 afc[4];
        #pragma unroll
        for (int q = 0; q < 4; ++q) afc[q] = floatx4{0.f, 0.f, 0.f, 0.f};

        const h16* arow = h_out + (base_row + lrow) * NB_FC1;

        auto ld = [&](int i, half8& a, half8 (&b)[4]) {   // kt = w*30 + i
            const int ktg = w * 30 + i;
            const int k0  = ktg * 32 + lgrp * 8;
            a = *(const half8*)(arow + k0);
            #pragma unroll
            for (int q = 0; q < 4; ++q) {
                const int n = q * 16 + lrow;
                b[q] = 0;
                if (n < 60)   // WcT[ktg][n][lgrp*8]: wave reads contiguous 1KB
                    b[q] = *(const half8*)(WcT + ((size_t)ktg * 64 + n) * 32 + lgrp * 8);
            }
        };
        auto mm4 = [&](const half8& a, const half8 (&b)[4]) {
            #pragma unroll
            for (int q = 0; q < 4; ++q)
                afc[q] = __builtin_amdgcn_mfma_f32_16x16x32_f16(a, b[q], afc[q], 0, 0, 0);
        };

        half8 a0, a1, a2, b0[4], b1[4], b2[4];
        ld(0, a0, b0);
        ld(1, a1, b1);
        #pragma unroll 1
        for (int i = 0; i < 30; i += 3) {            // 30 % 3 == 0
            ld(i + 2, a2, b2);                       // distance-2 prefetch
            mm4(a0, b0);
            if (i + 3 < 30) ld(i + 3, a0, b0);
            mm4(a1, b1);
            if (i + 4 < 30) ld(i + 4, a1, b1);
            mm4(a2, b2);
        }

        // 8-wave reduction through the (dead) ring LDS: 8*4*16*16 f32 = 16KB
        float* red = (float*)&hist[0][0][0];
        #pragma unroll
        for (int q = 0; q < 4; ++q)
            #pragma unroll
            for (int r = 0; r < 4; ++r)
                red[(((w * 4 + q) * 16) + (lgrp * 4 + r)) * 16 + lrow] = afc[q][r];
        __syncthreads();

        #pragma unroll
        for (int s = 0; s < 2; ++s) {
            const int idx = tid + 512 * s;       // 16 rows x 64 cols
            const int row = idx >> 6, col = idx & 63;
            if (col < 60) {
                const int q = col >> 4, cin = col & 15;
                float v = 0.f;
                #pragma unroll
                for (int ww = 0; ww < 8; ++ww)
                    v += red[(((ww * 4 + q) * 16) + row) * 16 + cin];
                out[(base_row + row) * 60 + col] = v + bcv[col];
            }
        }
    }
}

// ---------------------------------------------------------------------------
// Merged head-precompute kernel, grid 180:
//  blocks 0..119 : WcT[kt][64][32] = folded head weight, K-major layout
//  blocks 120..179: bc[m] = W_fc2[m]@b_fc1 + b_fc2[m] (m = bid-120)
// ---------------------------------------------------------------------------
__global__ __launch_bounds__(256, 2)
void head_kernel(const float* __restrict__ W_fc1,   // [512][7680]
                 const float* __restrict__ W_fc2,   // [60][512]
                 const float* __restrict__ b_fc1,   // [512]
                 const float* __restrict__ b_fc2,   // [60]
                 h16* __restrict__ WcT,             // [240][64][32]
                 float* __restrict__ bc)            // [60]
{
    const int tid  = threadIdx.x;
    if (blockIdx.x >= 120) {
        const int m = blockIdx.x - 120;
        const int t = tid;
        float p = W_fc2[m * 512 + t] * b_fc1[t] + W_fc2[m * 512 + 256 + t] * b_fc1[256 + t];
        #pragma unroll
        for (int off = 1; off < 64; off <<= 1) p += __shfl_xor(p, off);
        __shared__ float sred[4];
        if ((t & 63) == 0) sred[t >> 6] = p;
        __syncthreads();
        if (t == 0) bc[m] = sred[0] + sred[1] + sred[2] + sred[3] + b_fc2[m];
        return;
    }

    const int wv   = tid >> 6;
    const int lane = tid & 63;
    const int lrow = lane & 15;
    const int lgrp = lane >> 4;
    const int j0   = blockIdx.x * 64 + wv * 16;   // this wave's 16 output cols

    floatx4 acc[4];
    #pragma unroll
    for (int mt = 0; mt < 4; ++mt) acc[mt] = floatx4{0.f, 0.f, 0.f, 0.f};

    for (int kt = 0; kt < 16; ++kt) {
        const int k0 = kt * 32 + lgrp * 8;
        half8 bf;
        #pragma unroll
        for (int i = 0; i < 8; ++i)
            bf[i] = (h16)W_fc1[(size_t)(k0 + i) * NB_FC1 + j0 + lrow];
        #pragma unroll
        for (int mt = 0; mt < 4; ++mt) {
            const int m = mt * 16 + lrow;
            half8 af = {};
            if (m < 60) {
                const float* p = W_fc2 + (size_t)m * 512 + k0;
                const floatx4 f0 = *(const floatx4*)(p);
                const floatx4 f1 = *(const floatx4*)(p + 4);
                const auto p0 = __builtin_amdgcn_cvt_pkrtz(f0[0], f0[1]);
                const auto p1 = __builtin_amdgcn_cvt_pkrtz(f0[2], f0[3]);
                const auto p2 = __builtin_amdgcn_cvt_pkrtz(f1[0], f1[1]);
                const auto p3 = __builtin_amdgcn_cvt_pkrtz(f1[2], f1[3]);
                af[0] = (h16)p0[0]; af[1] = (h16)p0[1]; af[2] = (h16)p1[0]; af[3] = (h16)p1[1];
                af[4] = (h16)p2[0]; af[5] = (h16)p2[1]; af[6] = (h16)p3[0]; af[7] = (h16)p3[1];
            }
            acc[mt] = __builtin_amdgcn_mfma_f32_16x16x32_f16(af, bf, acc[mt], 0, 0, 0);
        }
    }

    // D[row m = mt*16+lgrp*4+r][col j = j0+lrow] -> WcT[(j>>5)][m][j&31]
    #pragma unroll
    for (int mt = 0; mt < 4; ++mt)
        #pragma unroll
        for (int r = 0; r < 4; ++r) {
            const int m = mt * 16 + lgrp * 4 + r;
            const int j = j0 + lrow;
            if (m < 60)
                WcT[((size_t)(j >> 5) * 64 + m) * 32 + (j & 31)] = (h16)acc[mt][r];
        }
}

extern "C" void kernel_launch(void* const* d_in, const int* in_sizes, int n_in,
                              void* d_out, int out_size, void* d_ws, size_t ws_size,
                              hipStream_t stream)
{
    const float* X      = (const float*)d_in[0];
    const float* W_ih1  = (const float*)d_in[1];
    const float* W_hh1  = (const float*)d_in[2];
    const float* b_ih1  = (const float*)d_in[3];
    const float* b_hh1  = (const float*)d_in[4];
    const float* W_ih2  = (const float*)d_in[5];
    const float* W_hh2  = (const float*)d_in[6];
    const float* b_ih2  = (const float*)d_in[7];
    const float* b_hh2  = (const float*)d_in[8];
    const float* W_fc1  = (const float*)d_in[9];
    const float* b_fc1  = (const float*)d_in[10];
    const float* W_fc2  = (const float*)d_in[11];
    const float* b_fc2  = (const float*)d_in[12];

    // workspace: h1 (63MB) | h2 (63MB) | WcT (0.94MB, [240][64][32]) | bc
    h16* h1  = (h16*)d_ws;
    h16* h2  = h1 + (size_t)4096 * NB_FC1;
    h16* WcT = h2 + (size_t)4096 * NB_FC1;
    float* bc = (float*)(WcT + (size_t)NKT * 64 * 32);

    head_kernel<<<180, 256, 0, stream>>>(W_fc1, W_fc2, b_fc1, b_fc2, WcT, bc);
    lstm_layer<64,  true,  false><<<256, 512, 0, stream>>>(
        (const void*)X,  W_ih1, W_hh1, b_ih1, b_hh1, h1, nullptr, nullptr, nullptr);
    lstm_layer<128, false, true ><<<256, 512, 0, stream>>>(
        (const void*)h1, W_ih2, W_hh2, b_ih2, b_hh2, h2, WcT, bc, (float*)d_out);
}